// Round 2
// baseline (742.815 us; speedup 1.0000x reference)
//
#include <hip/hip_runtime.h>

// Scaling-and-squaring integration of velocity fields.
// vel: [2, 160, 192, 160, 3] f32.  v0 = vel / 2^7;  7x: v = v + warp(v, v).
// Each step: dst[p] = src[p] + trilerp(src, p + src[p]) (coords clamped).
// Step 1 fuses the 2^-7 scale (power of two => bit-exact commute through lerp).
// Ping-pong: vel->out, out->ws, ws->out, out->ws, ws->out, out->ws, ws->out.
// ws needs 2*160*192*160*3*4 = 117,964,800 bytes.

#define DD 160
#define HH 192
#define WW 160
#define VOX (DD * HH * WW)      // 4,915,200 voxels per batch
#define NB 2
#define FIELD (VOX * 3)         // floats per batch

__device__ __forceinline__ void ld3(const float* __restrict__ p,
                                    float& a, float& b, float& c) {
    a = p[0]; b = p[1]; c = p[2];
}

__launch_bounds__(256)
__global__ void step_kernel(const float* __restrict__ src,
                            float* __restrict__ dst, float s) {
    int idx = blockIdx.x * 256 + threadIdx.x;   // voxel id over both batches
    if (idx >= NB * VOX) return;
    int b  = idx / VOX;
    int r  = idx - b * VOX;                     // voxel within batch
    int d  = r / (HH * WW);
    int r2 = r - d * (HH * WW);
    int h  = r2 / WW;
    int w  = r2 - h * WW;

    const float* __restrict__ v = src + (size_t)b * FIELD;
    float* __restrict__ o       = dst + (size_t)b * FIELD;

    int base = r * 3;
    float rv0 = v[base + 0];
    float rv1 = v[base + 1];
    float rv2 = v[base + 2];

    // sample location = grid + s*v, clamped to [0, dim-1]
    float x = fminf(fmaxf((float)d + s * rv0, 0.0f), (float)(DD - 1));
    float y = fminf(fmaxf((float)h + s * rv1, 0.0f), (float)(HH - 1));
    float z = fminf(fmaxf((float)w + s * rv2, 0.0f), (float)(WW - 1));

    float xf = floorf(x), yf = floorf(y), zf = floorf(z);
    int x0 = (int)xf, y0 = (int)yf, z0 = (int)zf;
    int x1 = min(x0 + 1, DD - 1);
    int y1 = min(y0 + 1, HH - 1);
    int z1 = min(z0 + 1, WW - 1);
    float wx = x - xf, wy = y - yf, wz = z - zf;
    float iwx = 1.0f - wx, iwy = 1.0f - wy, iwz = 1.0f - wz;

    // row base offsets (floats) for the 4 (x,y) corner rows
    int ro00 = ((x0 * HH + y0) * WW) * 3;
    int ro01 = ((x0 * HH + y1) * WW) * 3;
    int ro10 = ((x1 * HH + y0) * WW) * 3;
    int ro11 = ((x1 * HH + y1) * WW) * 3;
    int zo0 = z0 * 3, zo1 = z1 * 3;

    float a000, b000, c000, a001, b001, c001;
    float a010, b010, c010, a011, b011, c011;
    float a100, b100, c100, a101, b101, c101;
    float a110, b110, c110, a111, b111, c111;
    ld3(v + ro00 + zo0, a000, b000, c000);
    ld3(v + ro00 + zo1, a001, b001, c001);
    ld3(v + ro01 + zo0, a010, b010, c010);
    ld3(v + ro01 + zo1, a011, b011, c011);
    ld3(v + ro10 + zo0, a100, b100, c100);
    ld3(v + ro10 + zo1, a101, b101, c101);
    ld3(v + ro11 + zo0, a110, b110, c110);
    ld3(v + ro11 + zo1, a111, b111, c111);

    // trilinear lerp per channel (mirrors reference op order)
    float f0, f1, f2;
    {
        float c00 = a000 * iwz + a001 * wz;
        float c01 = a010 * iwz + a011 * wz;
        float c10 = a100 * iwz + a101 * wz;
        float c11 = a110 * iwz + a111 * wz;
        float c0 = c00 * iwy + c01 * wy;
        float c1 = c10 * iwy + c11 * wy;
        f0 = c0 * iwx + c1 * wx;
    }
    {
        float c00 = b000 * iwz + b001 * wz;
        float c01 = b010 * iwz + b011 * wz;
        float c10 = b100 * iwz + b101 * wz;
        float c11 = b110 * iwz + b111 * wz;
        float c0 = c00 * iwy + c01 * wy;
        float c1 = c10 * iwy + c11 * wy;
        f1 = c0 * iwx + c1 * wx;
    }
    {
        float c00 = c000 * iwz + c001 * wz;
        float c01 = c010 * iwz + c011 * wz;
        float c10 = c100 * iwz + c101 * wz;
        float c11 = c110 * iwz + c111 * wz;
        float c0 = c00 * iwy + c01 * wy;
        float c1 = c10 * iwy + c11 * wy;
        f2 = c0 * iwx + c1 * wx;
    }

    // dst = s*(self + interp); exact vs reference since s is a power of two
    o[base + 0] = s * (rv0 + f0);
    o[base + 1] = s * (rv1 + f1);
    o[base + 2] = s * (rv2 + f2);
}

extern "C" void kernel_launch(void* const* d_in, const int* in_sizes, int n_in,
                              void* d_out, int out_size, void* d_ws, size_t ws_size,
                              hipStream_t stream) {
    const float* vel = (const float*)d_in[0];
    float* out = (float*)d_out;
    float* ws  = (float*)d_ws;   // needs >= 117,964,800 bytes

    const int nthreads = NB * VOX;
    const int blocks = (nthreads + 255) / 256;

    // step 1 (fused 2^-7 scale), then 6 more; parity ends in d_out.
    step_kernel<<<blocks, 256, 0, stream>>>(vel, out, 1.0f / 128.0f);
    step_kernel<<<blocks, 256, 0, stream>>>(out, ws, 1.0f);
    step_kernel<<<blocks, 256, 0, stream>>>(ws, out, 1.0f);
    step_kernel<<<blocks, 256, 0, stream>>>(out, ws, 1.0f);
    step_kernel<<<blocks, 256, 0, stream>>>(ws, out, 1.0f);
    step_kernel<<<blocks, 256, 0, stream>>>(out, ws, 1.0f);
    step_kernel<<<blocks, 256, 0, stream>>>(ws, out, 1.0f);
}